// Round 1
// baseline (103.569 us; speedup 1.0000x reference)
//
#include <hip/hip_runtime.h>

typedef __bf16 bf16x8 __attribute__((ext_vector_type(8)));
typedef float  f32x16 __attribute__((ext_vector_type(16)));

#define HW      4096
#define CDIM    64
#define KCODES  512
#define PBLK    512      // positions per block
#define TPB     512      // threads per block
#define NPOS    131072

// Scores: s'_nk = 1 + ||e_k||^2 - 2 z_n . e_k  (all > 0 since |2 z.e| <= 0.36)
// argmin via u32 min of (bits(s') & ~0x1FF) | k   (positive floats order as u32)
// loss_n = ||z_n||^2 + (minscore - 1);  total * 1.25/8388608

__global__ __launch_bounds__(TPB, 2)
void vqvae_kernel(const float* __restrict__ x,
                  const float* __restrict__ cb,
                  float* __restrict__ out,
                  float* __restrict__ loss_out)
{
    // B-fragments of (-2e) bf16: [chunk(32 codes)][kstep s][lane] -> 8 bf16 (16B)
    __shared__ bf16x8 cbB[16][4][64];          // 64 KB
    // A-fragments of z bf16: [posgroup(32 pos)][kstep s][lane]
    __shared__ bf16x8 zB [16][4][64];          // 64 KB
    __shared__ float    ecb[KCODES];           // 1 + ||e||^2
    __shared__ unsigned minu[PBLK];
    __shared__ float    red[8];

    const int t   = threadIdx.x;
    const int l   = t & 63;
    const int w   = t >> 6;
    const int n0  = blockIdx.x * PBLK;
    const int b   = n0 >> 12;          // 4096 positions per batch image
    const int hw0 = n0 & (HW - 1);

    // ---- Phase 0a: codebook fragments (-2e -> bf16), fragment-order in LDS ----
    #pragma unroll
    for (int j = 0; j < 8; ++j) {
        int slot  = t + TPB * j;           // 0..4095 = ((chunk*4+s)*64+lane)
        int lane  = slot & 63;
        int s     = (slot >> 6) & 3;
        int chunk = slot >> 8;
        int code  = chunk * 32 + (lane & 31);
        int c0    = s * 16 + (lane >> 5) * 8;
        const float4* p = (const float4*)(cb + code * CDIM + c0);
        float4 a0 = p[0], a1 = p[1];
        bf16x8 v;
        v[0] = (__bf16)(-2.0f * a0.x); v[1] = (__bf16)(-2.0f * a0.y);
        v[2] = (__bf16)(-2.0f * a0.z); v[3] = (__bf16)(-2.0f * a0.w);
        v[4] = (__bf16)(-2.0f * a1.x); v[5] = (__bf16)(-2.0f * a1.y);
        v[6] = (__bf16)(-2.0f * a1.z); v[7] = (__bf16)(-2.0f * a1.w);
        cbB[chunk][s][lane] = v;
    }

    // ---- Phase 0b: ecb[k] = 1 + ||e_k||^2 (fp32), one code per thread ----
    {
        const float4* p = (const float4*)(cb + t * CDIM);
        float ssum = 0.f;
        #pragma unroll
        for (int q4 = 0; q4 < 16; ++q4) {
            float4 a = p[q4];
            ssum = fmaf(a.x, a.x, ssum); ssum = fmaf(a.y, a.y, ssum);
            ssum = fmaf(a.z, a.z, ssum); ssum = fmaf(a.w, a.w, ssum);
        }
        ecb[t] = 1.0f + ssum;
    }

    // ---- Phase 0c: z fragments (bf16) + ||z||^2 (fp32); thread t <-> position t ----
    float zsq = 0.f;
    {
        const float* xb = x + (b * CDIM) * HW + hw0 + t;   // coalesced over t
        #pragma unroll
        for (int s = 0; s < 4; ++s)
        #pragma unroll
        for (int h = 0; h < 2; ++h) {
            bf16x8 v;
            #pragma unroll
            for (int i = 0; i < 8; ++i) {
                float f = xb[(s * 16 + h * 8 + i) * HW];
                zsq = fmaf(f, f, zsq);
                v[i] = (__bf16)f;
            }
            zB[t >> 5][s][(t & 31) + 32 * h] = v;
        }
    }
    __syncthreads();

    // ---- Phase 1: MFMA 32x32x16 + in-register running u32-argmin ----
    bf16x8 az[2][4];
    #pragma unroll
    for (int g = 0; g < 2; ++g)
        #pragma unroll
        for (int s = 0; s < 4; ++s)
            az[g][s] = zB[2 * w + g][s][l];

    unsigned urun[2][16];
    #pragma unroll
    for (int g = 0; g < 2; ++g)
        #pragma unroll
        for (int i = 0; i < 16; ++i)
            urun[g][i] = 0xFFFFFFFFu;

    for (int chunk = 0; chunk < 16; ++chunk) {
        bf16x8 bb0 = cbB[chunk][0][l];
        bf16x8 bb1 = cbB[chunk][1][l];
        bf16x8 bb2 = cbB[chunk][2][l];
        bf16x8 bb3 = cbB[chunk][3][l];
        float bias = ecb[chunk * 32 + (l & 31)];
        f32x16 acc0, acc1;
        #pragma unroll
        for (int i = 0; i < 16; ++i) { acc0[i] = bias; acc1[i] = bias; }
        acc0 = __builtin_amdgcn_mfma_f32_32x32x16_bf16(az[0][0], bb0, acc0, 0, 0, 0);
        acc1 = __builtin_amdgcn_mfma_f32_32x32x16_bf16(az[1][0], bb0, acc1, 0, 0, 0);
        acc0 = __builtin_amdgcn_mfma_f32_32x32x16_bf16(az[0][1], bb1, acc0, 0, 0, 0);
        acc1 = __builtin_amdgcn_mfma_f32_32x32x16_bf16(az[1][1], bb1, acc1, 0, 0, 0);
        acc0 = __builtin_amdgcn_mfma_f32_32x32x16_bf16(az[0][2], bb2, acc0, 0, 0, 0);
        acc1 = __builtin_amdgcn_mfma_f32_32x32x16_bf16(az[1][2], bb2, acc1, 0, 0, 0);
        acc0 = __builtin_amdgcn_mfma_f32_32x32x16_bf16(az[0][3], bb3, acc0, 0, 0, 0);
        acc1 = __builtin_amdgcn_mfma_f32_32x32x16_bf16(az[1][3], bb3, acc1, 0, 0, 0);
        unsigned kor = (unsigned)(chunk * 32 + (l & 31));
        #pragma unroll
        for (int i = 0; i < 16; ++i) {
            unsigned u0 = (__float_as_uint(acc0[i]) & 0xFFFFFE00u) | kor;
            unsigned u1 = (__float_as_uint(acc1[i]) & 0xFFFFFE00u) | kor;
            urun[0][i] = (u0 < urun[0][i]) ? u0 : urun[0][i];
            urun[1][i] = (u1 < urun[1][i]) ? u1 : urun[1][i];
        }
    }

    // ---- Phase 2: cross-lane min over the 32 code-columns, publish per-position ----
    #pragma unroll
    for (int g = 0; g < 2; ++g)
        #pragma unroll
        for (int i = 0; i < 16; ++i) {
            unsigned u = urun[g][i];
            #pragma unroll
            for (int m = 1; m <= 16; m <<= 1) {
                unsigned o = __shfl_xor(u, m, 64);
                u = (o < u) ? o : u;
            }
            urun[g][i] = u;
        }
    if ((l & 31) == 0) {
        int h = l >> 5;
        #pragma unroll
        for (int g = 0; g < 2; ++g)
            #pragma unroll
            for (int i = 0; i < 16; ++i)
                minu[(2 * w + g) * 32 + (i & 3) + 8 * (i >> 2) + 4 * h] = urun[g][i];
    }
    __syncthreads();

    // ---- Phase 3: gather + coalesced store + loss ----
    unsigned u = minu[t];
    int   k      = (int)(u & 511u);
    float sprime = __uint_as_float(u & 0xFFFFFE00u);
    float lossv  = zsq + (sprime - 1.0f);

    {
        float* ob = out + (b * CDIM) * HW + hw0 + t;   // coalesced over t
        int chunk = k >> 5;
        int klane = k & 31;
        #pragma unroll
        for (int s = 0; s < 4; ++s)
        #pragma unroll
        for (int h = 0; h < 2; ++h) {
            bf16x8 q = cbB[chunk][s][klane + 32 * h];  // holds -2e
            #pragma unroll
            for (int i = 0; i < 8; ++i)
                ob[(s * 16 + h * 8 + i) * HW] = -0.5f * (float)q[i];
        }
    }

    #pragma unroll
    for (int m = 1; m < 64; m <<= 1)
        lossv += __shfl_xor(lossv, m, 64);
    if (l == 0) red[w] = lossv;
    __syncthreads();
    if (t == 0) {
        float tot = 0.f;
        #pragma unroll
        for (int i = 0; i < 8; ++i) tot += red[i];
        atomicAdd(loss_out, tot * (1.25f / 8388608.0f));
    }
}

extern "C" void kernel_launch(void* const* d_in, const int* in_sizes, int n_in,
                              void* d_out, int out_size, void* d_ws, size_t ws_size,
                              hipStream_t stream) {
    const float* x   = (const float*)d_in[0];
    const float* cb  = (const float*)d_in[1];
    float* out  = (float*)d_out;
    float* loss = out + (out_size - 1);   // scalar loss is the last element
    hipMemsetAsync(loss, 0, sizeof(float), stream);
    vqvae_kernel<<<dim3(NPOS / PBLK), dim3(TPB), 0, stream>>>(x, cb, out, loss);
}